// Round 5
// baseline (1476.856 us; speedup 1.0000x reference)
//
#include <hip/hip_runtime.h>
#include <hip/hip_bf16.h>

#define N_NODES 50000
#define F_IN 256
#define HID 128
#define NH 8
#define DH 16
#define NE 800000
#define NM 3
#define NOUT 8
#define NEG 0.2f
#define NROWS (N_NODES * NM)   // 150000 semantic rows

// ---------------- CSR build: histogram / scan / scatter ----------------
__global__ __launch_bounds__(256) void k_hist(const int* __restrict__ dst,
                                              int* __restrict__ deg) {
    int e = blockIdx.x * 256 + threadIdx.x;
    int m = blockIdx.y;
    if (e >= NE) return;
    atomicAdd(&deg[m * N_NODES + dst[(size_t)m * NE + e]], 1);
}

__global__ __launch_bounds__(256) void k_scan(int* __restrict__ deg,
                                              int* __restrict__ offs) {
    int m = blockIdx.x;
    int* dm = deg + (size_t)m * N_NODES;
    int* om = offs + (size_t)m * (N_NODES + 1);
    __shared__ int part[256];
    __shared__ int basev[256];
    int t = threadIdx.x;
    const int CH = (N_NODES + 255) / 256;
    int lo = t * CH;
    int hi = lo + CH; if (hi > N_NODES) hi = N_NODES;
    int s = 0;
    for (int i = lo; i < hi; i++) s += dm[i];
    part[t] = s;
    __syncthreads();
    if (t == 0) {
        int run = 0;
        for (int i = 0; i < 256; i++) { basev[i] = run; run += part[i]; }
    }
    __syncthreads();
    int run = basev[t];
    for (int i = lo; i < hi; i++) {
        int c = dm[i];
        om[i] = run;
        dm[i] = run;   // cursor init
        run += c;
    }
    if (t == 255) om[N_NODES] = run;
}

__global__ __launch_bounds__(256) void k_scatter(const int* __restrict__ src,
                                                 const int* __restrict__ dst,
                                                 int* __restrict__ cursor,
                                                 int* __restrict__ ssrc) {
    int e = blockIdx.x * 256 + threadIdx.x;
    int m = blockIdx.y;
    if (e >= NE) return;
    int d = dst[(size_t)m * NE + e];
    int sv = src[(size_t)m * NE + e];
    int pos = atomicAdd(&cursor[m * N_NODES + d], 1);
    ssrc[(size_t)m * NE + pos] = sv;
}

// ---------------- K1: h = feat @ W_fc + b  (16 rows/wave, scalar row loads) ----
__global__ __launch_bounds__(256) void k_fc(const float* __restrict__ feat,
                                            const float* __restrict__ Wfc,
                                            const float* __restrict__ bfc,
                                            float* __restrict__ h) {
    int l = threadIdx.x & 63;
    int wid = __builtin_amdgcn_readfirstlane(threadIdx.x >> 6);
    int r0 = (blockIdx.x * 4 + wid) * 16;
    float acc0[16], acc1[16];
    #pragma unroll
    for (int rr = 0; rr < 16; rr++) { acc0[rr] = 0.f; acc1[rr] = 0.f; }
    #pragma unroll 4
    for (int k = 0; k < F_IN; k++) {
        float w0 = Wfc[k * HID + l];
        float w1 = Wfc[k * HID + l + 64];
        #pragma unroll
        for (int rr = 0; rr < 16; rr++) {
            int r = r0 + rr; if (r > N_NODES - 1) r = N_NODES - 1;
            float a = feat[(size_t)r * F_IN + k];   // wave-uniform -> s_load
            acc0[rr] += a * w0;
            acc1[rr] += a * w1;
        }
    }
    float b0 = bfc[l], b1 = bfc[l + 64];
    #pragma unroll
    for (int rr = 0; rr < 16; rr++) {
        int r = r0 + rr;
        if (r < N_NODES) {
            h[(size_t)r * HID + l]      = acc0[rr] + b0;
            h[(size_t)r * HID + l + 64] = acc1[rr] + b1;
        }
    }
}

// ---------------- K2: fs = h@Wsrc, el/er  (16 rows/wave) ----------------
__global__ __launch_bounds__(256) void k_proj(const float* __restrict__ h,
                                              const float* __restrict__ Wsrc,
                                              const float* __restrict__ Wdst,
                                              const float* __restrict__ al,
                                              const float* __restrict__ ar,
                                              float* __restrict__ fs,
                                              float* __restrict__ el,
                                              float* __restrict__ er) {
    int l = threadIdx.x & 63;
    int wid = __builtin_amdgcn_readfirstlane(threadIdx.x >> 6);
    int r0 = (blockIdx.x * 4 + wid) * 16;
    float a0[16], a1[16], c0[16], c1[16];
    #pragma unroll
    for (int rr = 0; rr < 16; rr++) { a0[rr]=0.f; a1[rr]=0.f; c0[rr]=0.f; c1[rr]=0.f; }
    #pragma unroll 4
    for (int k = 0; k < HID; k++) {
        float ws0 = Wsrc[k * HID + l];
        float ws1 = Wsrc[k * HID + l + 64];
        float wd0 = Wdst[k * HID + l];
        float wd1 = Wdst[k * HID + l + 64];
        #pragma unroll
        for (int rr = 0; rr < 16; rr++) {
            int r = r0 + rr; if (r > N_NODES - 1) r = N_NODES - 1;
            float hv = h[(size_t)r * HID + k];   // wave-uniform -> s_load
            a0[rr] += hv * ws0;
            a1[rr] += hv * ws1;
            c0[rr] += hv * wd0;
            c1[rr] += hv * wd1;
        }
    }
    float al0 = al[l], al1 = al[l + 64];
    float ar0 = ar[l], ar1 = ar[l + 64];
    int seg = l & 15;
    #pragma unroll
    for (int rr = 0; rr < 16; rr++) {
        int r = r0 + rr;
        bool ok = (r < N_NODES);
        if (ok) {
            fs[(size_t)r * HID + l]      = a0[rr];
            fs[(size_t)r * HID + l + 64] = a1[rr];
        }
        // el/er: per-head (16-j) reductions within 16-lane segments
        float v0 = a0[rr] * al0, v1 = a1[rr] * al1;
        float u0 = c0[rr] * ar0, u1 = c1[rr] * ar1;
        #pragma unroll
        for (int o = 8; o > 0; o >>= 1) {
            v0 += __shfl_down(v0, o, 16);
            v1 += __shfl_down(v1, o, 16);
            u0 += __shfl_down(u0, o, 16);
            u1 += __shfl_down(u1, o, 16);
        }
        if (ok && seg == 0) {
            int hh = l >> 4;           // 0..3
            el[r * NH + hh]     = v0;
            el[r * NH + hh + 4] = v1;
            er[r * NH + hh]     = u0;
            er[r * NH + hh + 4] = u1;
        }
    }
}

// ---------------- K3: per-dst GAT aggregation; stores ELU(z) ----------------
__global__ __launch_bounds__(128) void k_gat(const int* __restrict__ ssrc,
                                             const int* __restrict__ offs,
                                             const float* __restrict__ el,
                                             const float* __restrict__ er,
                                             const float* __restrict__ fs,
                                             float* __restrict__ z, int m) {
    __shared__ float lds_part[128];
    __shared__ float inv_sum[NH];
    int d = blockIdx.x;
    int j = threadIdx.x;
    int s0 = offs[d], s1 = offs[d + 1];
    int t = j >> 3, hh2 = j & 7;
    float erd2 = er[d * NH + hh2];
    float part = 0.f;
    for (int i = s0 + t; i < s1; i += 16) {
        int s = ssrc[i];
        float x = el[s * NH + hh2] + erd2;
        x = (x >= 0.f) ? x : NEG * x;
        part += __expf(x);
    }
    lds_part[j] = part;
    __syncthreads();
    if (j < NH) {
        float acc = 0.f;
        #pragma unroll
        for (int t2 = 0; t2 < 16; t2++) acc += lds_part[t2 * 8 + j];
        inv_sum[j] = 1.f / fmaxf(acc, 1e-9f);
    }
    __syncthreads();
    int hh = j >> 4;
    float erd = er[d * NH + hh];
    float inv = inv_sum[hh];
    float acc = 0.f;
    for (int i = s0; i < s1; i++) {
        int s = ssrc[i];
        float x = el[s * NH + hh] + erd;
        x = (x >= 0.f) ? x : NEG * x;
        float alpha = __expf(x) * inv;
        acc += fs[(size_t)s * HID + j] * alpha;
    }
    // store post-ELU (reference's z is elu(hm); both consumers use elu'd z)
    z[(size_t)(d * NM + m) * HID + j] = (acc > 0.f) ? acc : (__expf(acc) - 1.f);
}

// ---------------- K4: w[r] = tanh(zel[r]@Wsem1 + b) @ wsem2  (16 rows/wave) ----
__global__ __launch_bounds__(256) void k_semw(const float* __restrict__ zel,
                                              const float* __restrict__ W1,
                                              const float* __restrict__ b1,
                                              const float* __restrict__ ws2,
                                              float* __restrict__ w) {
    int l = threadIdx.x & 63;
    int wid = __builtin_amdgcn_readfirstlane(threadIdx.x >> 6);
    int r0 = (blockIdx.x * 4 + wid) * 16;
    float acc0[16], acc1[16];
    #pragma unroll
    for (int rr = 0; rr < 16; rr++) { acc0[rr] = 0.f; acc1[rr] = 0.f; }
    #pragma unroll 4
    for (int k = 0; k < HID; k++) {
        float w0 = W1[k * HID + l];
        float w1 = W1[k * HID + l + 64];
        #pragma unroll
        for (int rr = 0; rr < 16; rr++) {
            int r = r0 + rr; if (r > NROWS - 1) r = NROWS - 1;
            float zv = zel[(size_t)r * HID + k];   // wave-uniform -> s_load
            acc0[rr] += zv * w0;
            acc1[rr] += zv * w1;
        }
    }
    float bb0 = b1[l], bb1 = b1[l + 64];
    float s0 = ws2[l], s1 = ws2[l + 64];
    #pragma unroll
    for (int rr = 0; rr < 16; rr++) {
        float v = tanhf(acc0[rr] + bb0) * s0 + tanhf(acc1[rr] + bb1) * s1;
        #pragma unroll
        for (int o = 32; o > 0; o >>= 1) v += __shfl_down(v, o, 64);
        int r = r0 + rr;
        if (l == 0 && r < NROWS) w[r] = v;
    }
}

// ---------------- K5: beta softmax + fused + out ----------------
__global__ __launch_bounds__(256) void k_comb(const float* __restrict__ zel,
                                              const float* __restrict__ w,
                                              const float* __restrict__ Wout,
                                              const float* __restrict__ bout,
                                              float* __restrict__ out) {
    __shared__ float fusedL[2][HID];
    int half = threadIdx.x >> 7;
    int j = threadIdx.x & 127;
    int n = blockIdx.x * 2 + half;
    float w0 = w[n * NM + 0];
    float w1 = w[n * NM + 1];
    float w2 = w[n * NM + 2];
    float mx = fmaxf(w0, fmaxf(w1, w2));
    float e0 = __expf(w0 - mx);
    float e1 = __expf(w1 - mx);
    float e2 = __expf(w2 - mx);
    float inv = 1.f / (e0 + e1 + e2);
    size_t base = (size_t)n * NM * HID;
    float f = (e0 * zel[base + j] + e1 * zel[base + HID + j] + e2 * zel[base + 2 * HID + j]) * inv;
    fusedL[half][j] = f;
    __syncthreads();
    int c = j >> 4, t16 = j & 15;
    float p = 0.f;
    #pragma unroll
    for (int i = 0; i < 8; i++) {
        int jj = t16 + i * 16;
        p += fusedL[half][jj] * Wout[jj * NOUT + c];
    }
    #pragma unroll
    for (int o = 8; o > 0; o >>= 1) p += __shfl_down(p, o, 16);
    if (t16 == 0) out[n * NOUT + c] = p + bout[c];
}

extern "C" void kernel_launch(void* const* d_in, const int* in_sizes, int n_in,
                              void* d_out, int out_size, void* d_ws, size_t ws_size,
                              hipStream_t stream) {
    (void)in_sizes; (void)n_in; (void)out_size; (void)ws_size;
    const float* feat  = (const float*)d_in[0];
    const float* Wfc   = (const float*)d_in[1];
    const float* bfc   = (const float*)d_in[2];
    const float* Wsrc  = (const float*)d_in[3];
    const float* Wdst  = (const float*)d_in[4];
    const float* al    = (const float*)d_in[5];
    const float* ar    = (const float*)d_in[6];
    const float* Wsem1 = (const float*)d_in[7];
    const float* bsem1 = (const float*)d_in[8];
    const float* wsem2 = (const float*)d_in[9];
    const float* Wout  = (const float*)d_in[10];
    const float* bout  = (const float*)d_in[11];
    const int* srcI    = (const int*)d_in[12];
    const int* dstI    = (const int*)d_in[13];
    float* out = (float*)d_out;

    // workspace: fp32 h | z | fs | el | er | w, then int deg | offs | ssrc
    float* h    = (float*)d_ws;
    float* z    = h  + (size_t)N_NODES * HID;
    float* fs   = z  + (size_t)N_NODES * NM * HID;
    float* el   = fs + (size_t)N_NODES * HID;
    float* er   = el + (size_t)N_NODES * NH;
    float* wsc  = er + (size_t)N_NODES * NH;          // (N*3,) semantic scores
    int*   deg  = (int*)(wsc + (size_t)NROWS);
    int*   offs = deg  + (size_t)NM * N_NODES;
    int*   ssrc = offs + (size_t)NM * (N_NODES + 1);

    hipMemsetAsync(deg, 0, (size_t)NM * N_NODES * sizeof(int), stream);
    {
        dim3 g((NE + 255) / 256, NM);
        k_hist<<<g, 256, 0, stream>>>(dstI, deg);
        k_scan<<<NM, 256, 0, stream>>>(deg, offs);
        k_scatter<<<g, 256, 0, stream>>>(srcI, dstI, deg, ssrc);
    }

    k_fc<<<(N_NODES + 63) / 64, 256, 0, stream>>>(feat, Wfc, bfc, h);

    for (int m = 0; m < NM; m++) {
        k_proj<<<(N_NODES + 63) / 64, 256, 0, stream>>>(h, Wsrc + (size_t)m * HID * HID,
                                                        Wdst + (size_t)m * HID * HID,
                                                        al + m * NH * DH, ar + m * NH * DH,
                                                        fs, el, er);
        k_gat<<<N_NODES, 128, 0, stream>>>(ssrc + (size_t)m * NE,
                                           offs + (size_t)m * (N_NODES + 1),
                                           el, er, fs, z, m);
    }

    k_semw<<<(NROWS + 63) / 64, 256, 0, stream>>>(z, Wsem1, bsem1, wsem2, wsc);
    k_comb<<<N_NODES / 2, 256, 0, stream>>>(z, wsc, Wout, bout, out);
}

// Round 6
// 1306.528 us; speedup vs baseline: 1.1304x; 1.1304x over previous
//
#include <hip/hip_runtime.h>
#include <hip/hip_bf16.h>

#define N_NODES 50000
#define F_IN 256
#define HID 128
#define NH 8
#define DH 16
#define NE 800000
#define NM 3
#define NOUT 8
#define NEG 0.2f
#define NROWS (N_NODES * NM)   // 150000 semantic rows
#define LDA 68                 // padded LDS stride (68*4=272B, 16B-aligned, bank-safe)

// ---------------- CSR build: histogram / scan / scatter ----------------
__global__ __launch_bounds__(256) void k_hist(const int* __restrict__ dst,
                                              int* __restrict__ deg) {
    int e = blockIdx.x * 256 + threadIdx.x;
    int m = blockIdx.y;
    if (e >= NE) return;
    atomicAdd(&deg[m * N_NODES + dst[(size_t)m * NE + e]], 1);
}

__global__ __launch_bounds__(256) void k_scan(int* __restrict__ deg,
                                              int* __restrict__ offs) {
    int m = blockIdx.x;
    int* dm = deg + (size_t)m * N_NODES;
    int* om = offs + (size_t)m * (N_NODES + 1);
    __shared__ int part[256];
    __shared__ int basev[256];
    int t = threadIdx.x;
    const int CH = (N_NODES + 255) / 256;
    int lo = t * CH;
    int hi = lo + CH; if (hi > N_NODES) hi = N_NODES;
    int s = 0;
    for (int i = lo; i < hi; i++) s += dm[i];
    part[t] = s;
    __syncthreads();
    if (t == 0) {
        int run = 0;
        for (int i = 0; i < 256; i++) { basev[i] = run; run += part[i]; }
    }
    __syncthreads();
    int run = basev[t];
    for (int i = lo; i < hi; i++) {
        int c = dm[i];
        om[i] = run;
        dm[i] = run;   // cursor init
        run += c;
    }
    if (t == 255) om[N_NODES] = run;
}

__global__ __launch_bounds__(256) void k_scatter(const int* __restrict__ src,
                                                 const int* __restrict__ dst,
                                                 int* __restrict__ cursor,
                                                 int* __restrict__ ssrc) {
    int e = blockIdx.x * 256 + threadIdx.x;
    int m = blockIdx.y;
    if (e >= NE) return;
    int d = dst[(size_t)m * NE + e];
    int sv = src[(size_t)m * NE + e];
    int pos = atomicAdd(&cursor[m * N_NODES + d], 1);
    ssrc[(size_t)m * NE + pos] = sv;
}

// ---------------- K1: h = feat @ W_fc + b (LDS-tiled, 64 rows/block) ----------
__global__ __launch_bounds__(256) void k_fc(const float* __restrict__ A,
                                            const float* __restrict__ B,
                                            const float* __restrict__ bias,
                                            float* __restrict__ C) {
    __shared__ float As[128 * LDA];
    int tid = threadIdx.x;
    int tc = tid & 15, tr = tid >> 4;
    int r0 = blockIdx.x * 64;
    int j0 = tc * 8;
    int rowA = tid & 63;
    int kc = tid >> 6;
    float acc[4][8];
    #pragma unroll
    for (int i = 0; i < 4; i++)
        #pragma unroll
        for (int c = 0; c < 8; c++) acc[i][c] = 0.f;

    int gr = r0 + rowA; if (gr > N_NODES - 1) gr = N_NODES - 1;
    for (int ph = 0; ph < 2; ph++) {
        __syncthreads();
        const float* ap = A + (size_t)gr * F_IN + ph * 128 + kc * 32;
        #pragma unroll
        for (int i = 0; i < 8; i++) {
            float4 v = ((const float4*)ap)[i];
            int k = kc * 32 + i * 4;
            As[(k + 0) * LDA + rowA] = v.x;
            As[(k + 1) * LDA + rowA] = v.y;
            As[(k + 2) * LDA + rowA] = v.z;
            As[(k + 3) * LDA + rowA] = v.w;
        }
        __syncthreads();
        const float* bp = B + (size_t)(ph * 128) * HID + j0;
        #pragma unroll 4
        for (int k = 0; k < 128; k++) {
            float4 a4 = *(const float4*)&As[k * LDA + tr * 4];
            float4 b0 = *(const float4*)&bp[(size_t)k * HID];
            float4 b1 = *(const float4*)&bp[(size_t)k * HID + 4];
            float av[4] = {a4.x, a4.y, a4.z, a4.w};
            float bv[8] = {b0.x, b0.y, b0.z, b0.w, b1.x, b1.y, b1.z, b1.w};
            #pragma unroll
            for (int i = 0; i < 4; i++)
                #pragma unroll
                for (int c = 0; c < 8; c++) acc[i][c] += av[i] * bv[c];
        }
    }
    float bb[8];
    #pragma unroll
    for (int c = 0; c < 8; c++) bb[c] = bias[j0 + c];
    #pragma unroll
    for (int i = 0; i < 4; i++) {
        int row = r0 + tr * 4 + i;
        if (row < N_NODES) {
            float4 o0 = {acc[i][0] + bb[0], acc[i][1] + bb[1], acc[i][2] + bb[2], acc[i][3] + bb[3]};
            float4 o1 = {acc[i][4] + bb[4], acc[i][5] + bb[5], acc[i][6] + bb[6], acc[i][7] + bb[7]};
            *(float4*)&C[(size_t)row * HID + j0] = o0;
            *(float4*)&C[(size_t)row * HID + j0 + 4] = o1;
        }
    }
}

// ------- K2: fs = h@Wsrc (stored), fd = h@Wdst (el/er only, not stored) -------
__global__ __launch_bounds__(256) void k_proj(const float* __restrict__ A,
                                              const float* __restrict__ Bs,
                                              const float* __restrict__ Bd,
                                              const float* __restrict__ al,
                                              const float* __restrict__ ar,
                                              float* __restrict__ fs,
                                              float* __restrict__ el,
                                              float* __restrict__ er) {
    __shared__ float As[128 * LDA];
    int tid = threadIdx.x;
    int tc = tid & 15, tr = tid >> 4;
    int r0 = blockIdx.x * 64;
    int j0 = tc * 8;
    int rowA = tid & 63;
    int kc = tid >> 6;
    float as_[4][8], ad_[4][8];
    #pragma unroll
    for (int i = 0; i < 4; i++)
        #pragma unroll
        for (int c = 0; c < 8; c++) { as_[i][c] = 0.f; ad_[i][c] = 0.f; }

    int gr = r0 + rowA; if (gr > N_NODES - 1) gr = N_NODES - 1;
    const float* ap = A + (size_t)gr * HID + kc * 32;
    #pragma unroll
    for (int i = 0; i < 8; i++) {
        float4 v = ((const float4*)ap)[i];
        int k = kc * 32 + i * 4;
        As[(k + 0) * LDA + rowA] = v.x;
        As[(k + 1) * LDA + rowA] = v.y;
        As[(k + 2) * LDA + rowA] = v.z;
        As[(k + 3) * LDA + rowA] = v.w;
    }
    __syncthreads();
    const float* bps = Bs + j0;
    const float* bpd = Bd + j0;
    #pragma unroll 2
    for (int k = 0; k < 128; k++) {
        float4 a4 = *(const float4*)&As[k * LDA + tr * 4];
        float4 s0 = *(const float4*)&bps[(size_t)k * HID];
        float4 s1 = *(const float4*)&bps[(size_t)k * HID + 4];
        float4 d0 = *(const float4*)&bpd[(size_t)k * HID];
        float4 d1 = *(const float4*)&bpd[(size_t)k * HID + 4];
        float av[4] = {a4.x, a4.y, a4.z, a4.w};
        float sv[8] = {s0.x, s0.y, s0.z, s0.w, s1.x, s1.y, s1.z, s1.w};
        float dv[8] = {d0.x, d0.y, d0.z, d0.w, d1.x, d1.y, d1.z, d1.w};
        #pragma unroll
        for (int i = 0; i < 4; i++)
            #pragma unroll
            for (int c = 0; c < 8; c++) {
                as_[i][c] += av[i] * sv[c];
                ad_[i][c] += av[i] * dv[c];
            }
    }
    float alv[8], arv[8];
    #pragma unroll
    for (int c = 0; c < 8; c++) { alv[c] = al[j0 + c]; arv[c] = ar[j0 + c]; }
    int head = tc >> 1;
    #pragma unroll
    for (int i = 0; i < 4; i++) {
        int row = r0 + tr * 4 + i;
        bool ok = (row < N_NODES);
        if (ok) {
            float4 o0 = {as_[i][0], as_[i][1], as_[i][2], as_[i][3]};
            float4 o1 = {as_[i][4], as_[i][5], as_[i][6], as_[i][7]};
            *(float4*)&fs[(size_t)row * HID + j0] = o0;
            *(float4*)&fs[(size_t)row * HID + j0 + 4] = o1;
        }
        float pl = 0.f, pr = 0.f;
        #pragma unroll
        for (int c = 0; c < 8; c++) { pl += as_[i][c] * alv[c]; pr += ad_[i][c] * arv[c]; }
        pl += __shfl_xor(pl, 1);
        pr += __shfl_xor(pr, 1);
        if (ok && (tc & 1) == 0) {
            el[row * NH + head] = pl;
            er[row * NH + head] = pr;
        }
    }
}

// ---------------- K3: per-dst GAT aggregation; stores ELU(z) ----------------
__global__ __launch_bounds__(128) void k_gat(const int* __restrict__ ssrc,
                                             const int* __restrict__ offs,
                                             const float* __restrict__ el,
                                             const float* __restrict__ er,
                                             const float* __restrict__ fs,
                                             float* __restrict__ z, int m) {
    __shared__ float lds_part[128];
    __shared__ float inv_sum[NH];
    int d = blockIdx.x;
    int j = threadIdx.x;
    int s0 = offs[d], s1 = offs[d + 1];
    int t = j >> 3, hh2 = j & 7;
    float erd2 = er[d * NH + hh2];
    float part = 0.f;
    for (int i = s0 + t; i < s1; i += 16) {
        int s = ssrc[i];
        float x = el[s * NH + hh2] + erd2;
        x = (x >= 0.f) ? x : NEG * x;
        part += __expf(x);
    }
    lds_part[j] = part;
    __syncthreads();
    if (j < NH) {
        float acc = 0.f;
        #pragma unroll
        for (int t2 = 0; t2 < 16; t2++) acc += lds_part[t2 * 8 + j];
        inv_sum[j] = 1.f / fmaxf(acc, 1e-9f);
    }
    __syncthreads();
    int hh = j >> 4;
    float erd = er[d * NH + hh];
    float inv = inv_sum[hh];
    float acc = 0.f;
    for (int i = s0; i < s1; i++) {
        int s = ssrc[i];
        float x = el[s * NH + hh] + erd;
        x = (x >= 0.f) ? x : NEG * x;
        float alpha = __expf(x) * inv;
        acc += fs[(size_t)s * HID + j] * alpha;
    }
    z[(size_t)(d * NM + m) * HID + j] = (acc > 0.f) ? acc : (__expf(acc) - 1.f);
}

// -------- K4: w[r] = tanh(zel@W1 + b1) @ w2  (LDS-tiled, 64 rows/block) -------
__global__ __launch_bounds__(256) void k_semw(const float* __restrict__ A,
                                              const float* __restrict__ B,
                                              const float* __restrict__ b1,
                                              const float* __restrict__ ws2,
                                              float* __restrict__ w) {
    __shared__ float As[128 * LDA];
    int tid = threadIdx.x;
    int tc = tid & 15, tr = tid >> 4;
    int r0 = blockIdx.x * 64;
    int j0 = tc * 8;
    int rowA = tid & 63;
    int kc = tid >> 6;
    float acc[4][8];
    #pragma unroll
    for (int i = 0; i < 4; i++)
        #pragma unroll
        for (int c = 0; c < 8; c++) acc[i][c] = 0.f;

    int gr = r0 + rowA; if (gr > NROWS - 1) gr = NROWS - 1;
    const float* ap = A + (size_t)gr * HID + kc * 32;
    #pragma unroll
    for (int i = 0; i < 8; i++) {
        float4 v = ((const float4*)ap)[i];
        int k = kc * 32 + i * 4;
        As[(k + 0) * LDA + rowA] = v.x;
        As[(k + 1) * LDA + rowA] = v.y;
        As[(k + 2) * LDA + rowA] = v.z;
        As[(k + 3) * LDA + rowA] = v.w;
    }
    __syncthreads();
    const float* bp = B + j0;
    #pragma unroll 4
    for (int k = 0; k < 128; k++) {
        float4 a4 = *(const float4*)&As[k * LDA + tr * 4];
        float4 b0 = *(const float4*)&bp[(size_t)k * HID];
        float4 b1v = *(const float4*)&bp[(size_t)k * HID + 4];
        float av[4] = {a4.x, a4.y, a4.z, a4.w};
        float bv[8] = {b0.x, b0.y, b0.z, b0.w, b1v.x, b1v.y, b1v.z, b1v.w};
        #pragma unroll
        for (int i = 0; i < 4; i++)
            #pragma unroll
            for (int c = 0; c < 8; c++) acc[i][c] += av[i] * bv[c];
    }
    float bb[8], s2[8];
    #pragma unroll
    for (int c = 0; c < 8; c++) { bb[c] = b1[j0 + c]; s2[c] = ws2[j0 + c]; }
    #pragma unroll
    for (int i = 0; i < 4; i++) {
        float v = 0.f;
        #pragma unroll
        for (int c = 0; c < 8; c++) v += tanhf(acc[i][c] + bb[c]) * s2[c];
        #pragma unroll
        for (int o = 8; o > 0; o >>= 1) v += __shfl_down(v, o, 16);
        int row = r0 + tr * 4 + i;
        if (tc == 0 && row < NROWS) w[row] = v;
    }
}

// ---------------- K5: beta softmax + fused + out ----------------
__global__ __launch_bounds__(256) void k_comb(const float* __restrict__ zel,
                                              const float* __restrict__ w,
                                              const float* __restrict__ Wout,
                                              const float* __restrict__ bout,
                                              float* __restrict__ out) {
    __shared__ float fusedL[2][HID];
    int half = threadIdx.x >> 7;
    int j = threadIdx.x & 127;
    int n = blockIdx.x * 2 + half;
    float w0 = w[n * NM + 0];
    float w1 = w[n * NM + 1];
    float w2 = w[n * NM + 2];
    float mx = fmaxf(w0, fmaxf(w1, w2));
    float e0 = __expf(w0 - mx);
    float e1 = __expf(w1 - mx);
    float e2 = __expf(w2 - mx);
    float inv = 1.f / (e0 + e1 + e2);
    size_t base = (size_t)n * NM * HID;
    float f = (e0 * zel[base + j] + e1 * zel[base + HID + j] + e2 * zel[base + 2 * HID + j]) * inv;
    fusedL[half][j] = f;
    __syncthreads();
    int c = j >> 4, t16 = j & 15;
    float p = 0.f;
    #pragma unroll
    for (int i = 0; i < 8; i++) {
        int jj = t16 + i * 16;
        p += fusedL[half][jj] * Wout[jj * NOUT + c];
    }
    #pragma unroll
    for (int o = 8; o > 0; o >>= 1) p += __shfl_down(p, o, 16);
    if (t16 == 0) out[n * NOUT + c] = p + bout[c];
}

extern "C" void kernel_launch(void* const* d_in, const int* in_sizes, int n_in,
                              void* d_out, int out_size, void* d_ws, size_t ws_size,
                              hipStream_t stream) {
    (void)in_sizes; (void)n_in; (void)out_size; (void)ws_size;
    const float* feat  = (const float*)d_in[0];
    const float* Wfc   = (const float*)d_in[1];
    const float* bfc   = (const float*)d_in[2];
    const float* Wsrc  = (const float*)d_in[3];
    const float* Wdst  = (const float*)d_in[4];
    const float* al    = (const float*)d_in[5];
    const float* ar    = (const float*)d_in[6];
    const float* Wsem1 = (const float*)d_in[7];
    const float* bsem1 = (const float*)d_in[8];
    const float* wsem2 = (const float*)d_in[9];
    const float* Wout  = (const float*)d_in[10];
    const float* bout  = (const float*)d_in[11];
    const int* srcI    = (const int*)d_in[12];
    const int* dstI    = (const int*)d_in[13];
    float* out = (float*)d_out;

    float* h    = (float*)d_ws;
    float* z    = h  + (size_t)N_NODES * HID;
    float* fs   = z  + (size_t)N_NODES * NM * HID;
    float* el   = fs + (size_t)N_NODES * HID;
    float* er   = el + (size_t)N_NODES * NH;
    float* wsc  = er + (size_t)N_NODES * NH;
    int*   deg  = (int*)(wsc + (size_t)NROWS);
    int*   offs = deg  + (size_t)NM * N_NODES;
    int*   ssrc = offs + (size_t)NM * (N_NODES + 1);

    hipMemsetAsync(deg, 0, (size_t)NM * N_NODES * sizeof(int), stream);
    {
        dim3 g((NE + 255) / 256, NM);
        k_hist<<<g, 256, 0, stream>>>(dstI, deg);
        k_scan<<<NM, 256, 0, stream>>>(deg, offs);
        k_scatter<<<g, 256, 0, stream>>>(srcI, dstI, deg, ssrc);
    }

    k_fc<<<(N_NODES + 63) / 64, 256, 0, stream>>>(feat, Wfc, bfc, h);

    for (int m = 0; m < NM; m++) {
        k_proj<<<(N_NODES + 63) / 64, 256, 0, stream>>>(h, Wsrc + (size_t)m * HID * HID,
                                                        Wdst + (size_t)m * HID * HID,
                                                        al + m * NH * DH, ar + m * NH * DH,
                                                        fs, el, er);
        k_gat<<<N_NODES, 128, 0, stream>>>(ssrc + (size_t)m * NE,
                                           offs + (size_t)m * (N_NODES + 1),
                                           el, er, fs, z, m);
    }

    k_semw<<<(NROWS + 63) / 64, 256, 0, stream>>>(z, Wsem1, bsem1, wsem2, wsc);
    k_comb<<<N_NODES / 2, 256, 0, stream>>>(z, wsc, Wout, bout, out);
}